// Round 3
// baseline (2502.988 us; speedup 1.0000x reference)
//
#include <hip/hip_runtime.h>
#include <math.h>

// Problem constants (match reference)
#define NROWS 2048
#define NCENT 100000
#define DIM 128
#define KNN 200
#define NCLS 1000
#define GCONST 0.005f          // 1/(2*sigma^2), sigma=10
#define NBINS 128              // hist LDS = 64 rows * 128 * 4B = 32KB (total 48KB)
#define INV_BIN_W 0.25f        // bin width 4.0 on x = d2 - ||f||^2, range [-192, 320)
#define CAND_MAX 512
#define NSTRIPS 16
#define STRIP (NCENT / NSTRIPS) // 6250

struct Cand { float d2; int idx; };

// Monotone binning of d2, anchored per-row at ||f||^2. Clamp bins act as exact
// catch-alls. Bins only funnel candidates; final boundary ranking is float64.
__device__ __forceinline__ int bin_of(float d2, float fn) {
    float x = ((d2 - fn) + 192.0f) * INV_BIN_W;
    int b = (int)floorf(x);
    if (b < 0) b = 0;
    if (b > NBINS - 1) b = NBINS - 1;
    return b;
}

// Detect whether the labels buffer is int64 (little-endian: odd int32 words all
// zero) or int32, normalize to int32.
__global__ void k_detect(const int* __restrict__ labels_raw, int* __restrict__ flag) {
    if (threadIdx.x == 0 && blockIdx.x == 0) {
        int z = 1;
        for (int i = 1; i < 256; i += 2)
            if (labels_raw[i] != 0) { z = 0; break; }
        flag[0] = z;  // 1 => int64 layout
    }
}

__global__ void k_cvt_labels(const void* __restrict__ labels_raw, const int* __restrict__ flag,
                             int* __restrict__ labels32) {
    int i = blockIdx.x * blockDim.x + threadIdx.x;
    if (i >= NCENT) return;
    if (flag[0]) labels32[i] = (int)((const long long*)labels_raw)[i];
    else         labels32[i] = ((const int*)labels_raw)[i];
}

// One wave per row: ||row||^2 (shared by both GEMM passes so d2 is bit-identical).
__global__ void k_rownorm(const float* __restrict__ src, float* __restrict__ dst, int nrows) {
    int w = (blockIdx.x * blockDim.x + threadIdx.x) >> 6;
    int lane = threadIdx.x & 63;
    if (w >= nrows) return;
    const float* r = src + (size_t)w * DIM;
    float a = r[lane];
    float b = r[lane + 64];
    float s = a * a + b * b;
    #pragma unroll
    for (int off = 32; off > 0; off >>= 1) s += __shfl_down(s, off);
    if (lane == 0) dst[w] = s;
}

// Shared deterministic fp32 distance GEMM.
// PASS 1: per-row histogram of d2 bins. PASS 2: recompute bit-identical d2;
// bin < tau -> bulk scatter-add; bin == tau -> boundary candidate.
template <int PASS>
__global__ void __launch_bounds__(256)
gemm_pass(const float* __restrict__ feat, const float* __restrict__ cent,
          const float* __restrict__ weightv, const int* __restrict__ labels,
          const float* __restrict__ fnorm, const float* __restrict__ cnorm,
          unsigned int* __restrict__ gHist, const int* __restrict__ tauBin,
          float* __restrict__ gp, int* __restrict__ candCnt,
          Cand* __restrict__ cands)
{
    __shared__ float As[32 * 64];                               // [k][row] 8KB
    __shared__ float Bs[32 * 64];                               // [k][col] 8KB
    __shared__ unsigned int hist[(PASS == 1) ? 64 * NBINS : 1]; // 32KB in pass 1

    const int strip    = blockIdx.x;            // 16 strips of 6250 centres
    const int rowBase  = blockIdx.y * 64;       // 32 row tiles of 64
    const int tid      = threadIdx.x;           // 256 threads
    const int tr       = tid >> 4;              // 0..15 -> rows tr*4..tr*4+3
    const int tc       = tid & 15;              // 0..15 -> cols tc*4..tc*4+3
    const int stripEnd = (strip + 1) * STRIP;

    if (PASS == 1) {
        for (int i = tid; i < 64 * NBINS; i += 256) hist[i] = 0;
    }

    float fn[4];
    int tb[4];
    #pragma unroll
    for (int i = 0; i < 4; ++i) {
        int r = rowBase + tr * 4 + i;
        fn[i] = fnorm[r];
        if (PASS == 2) tb[i] = tauBin[r]; else tb[i] = 0;
    }
    __syncthreads();

    for (int ctBase = strip * STRIP; ctBase < stripEnd; ctBase += 64) {
        float acc[4][4];
        #pragma unroll
        for (int i = 0; i < 4; ++i)
            #pragma unroll
            for (int j = 0; j < 4; ++j) acc[i][j] = 0.0f;

        #pragma unroll 1
        for (int kb = 0; kb < DIM; kb += 32) {
            #pragma unroll
            for (int l = 0; l < 2; ++l) {
                int q = tid + l * 256;          // 0..511 float4 slots
                int row = q >> 3;
                int k4 = (q & 7) * 4;
                const float4 v = *(const float4*)(feat + (size_t)(rowBase + row) * DIM + kb + k4);
                As[(k4 + 0) * 64 + row] = v.x;
                As[(k4 + 1) * 64 + row] = v.y;
                As[(k4 + 2) * 64 + row] = v.z;
                As[(k4 + 3) * 64 + row] = v.w;
            }
            #pragma unroll
            for (int l = 0; l < 2; ++l) {
                int q = tid + l * 256;
                int crow = q >> 3;
                int k4 = (q & 7) * 4;
                int col = ctBase + crow;
                float4 v = make_float4(0.0f, 0.0f, 0.0f, 0.0f);
                if (col < stripEnd)
                    v = *(const float4*)(cent + (size_t)col * DIM + kb + k4);
                Bs[(k4 + 0) * 64 + crow] = v.x;
                Bs[(k4 + 1) * 64 + crow] = v.y;
                Bs[(k4 + 2) * 64 + crow] = v.z;
                Bs[(k4 + 3) * 64 + crow] = v.w;
            }
            __syncthreads();
            #pragma unroll
            for (int kk = 0; kk < 32; ++kk) {
                const float4 av = *(const float4*)(As + kk * 64 + tr * 4);
                const float4 bv = *(const float4*)(Bs + kk * 64 + tc * 4);
                acc[0][0] = fmaf(av.x, bv.x, acc[0][0]);
                acc[0][1] = fmaf(av.x, bv.y, acc[0][1]);
                acc[0][2] = fmaf(av.x, bv.z, acc[0][2]);
                acc[0][3] = fmaf(av.x, bv.w, acc[0][3]);
                acc[1][0] = fmaf(av.y, bv.x, acc[1][0]);
                acc[1][1] = fmaf(av.y, bv.y, acc[1][1]);
                acc[1][2] = fmaf(av.y, bv.z, acc[1][2]);
                acc[1][3] = fmaf(av.y, bv.w, acc[1][3]);
                acc[2][0] = fmaf(av.z, bv.x, acc[2][0]);
                acc[2][1] = fmaf(av.z, bv.y, acc[2][1]);
                acc[2][2] = fmaf(av.z, bv.z, acc[2][2]);
                acc[2][3] = fmaf(av.z, bv.w, acc[2][3]);
                acc[3][0] = fmaf(av.w, bv.x, acc[3][0]);
                acc[3][1] = fmaf(av.w, bv.y, acc[3][1]);
                acc[3][2] = fmaf(av.w, bv.z, acc[3][2]);
                acc[3][3] = fmaf(av.w, bv.w, acc[3][3]);
            }
            __syncthreads();
        }

        #pragma unroll
        for (int j = 0; j < 4; ++j) {
            int col = ctBase + tc * 4 + j;
            if (col >= stripEnd) continue;
            float cn = cnorm[col];
            #pragma unroll
            for (int i = 0; i < 4; ++i) {
                float d2 = fmaf(-2.0f, acc[i][j], fn[i] + cn);  // bit-identical both passes
                int b = bin_of(d2, fn[i]);
                if (PASS == 1) {
                    atomicAdd(&hist[(tr * 4 + i) * NBINS + b], 1u);
                } else {
                    int r = rowBase + tr * 4 + i;
                    if (b < tb[i]) {
                        float w = expf(weightv[col] - fmaxf(d2, 0.0f) * GCONST);
                        atomicAdd(&gp[(size_t)r * NCLS + labels[col]], w);
                    } else if (b == tb[i]) {
                        int pos = atomicAdd(&candCnt[r], 1);
                        if (pos < CAND_MAX) {
                            cands[(size_t)r * CAND_MAX + pos].d2 = d2;
                            cands[(size_t)r * CAND_MAX + pos].idx = col;
                        }
                    }
                }
            }
        }
    }

    if (PASS == 1) {
        __syncthreads();
        for (int i = tid; i < 64 * NBINS; i += 256) {
            unsigned int v = hist[i];
            if (v)
                atomicAdd(&gHist[(size_t)(rowBase + (i / NBINS)) * NBINS + (i % NBINS)], v);
        }
    }
}

// Find the bin containing the KNN-th smallest d2 per row + exact count below it.
__global__ void k_tau(const unsigned int* __restrict__ gHist,
                      int* __restrict__ tauBin, int* __restrict__ nless) {
    int row = blockIdx.x * blockDim.x + threadIdx.x;
    if (row >= NROWS) return;
    const unsigned int* h = gHist + (size_t)row * NBINS;
    unsigned int cum = 0;
    for (int b = 0; b < NBINS; ++b) {
        unsigned int v = h[b];
        if (cum + v >= KNN) { tauBin[row] = b; nless[row] = (int)cum; return; }
        cum += v;
    }
    tauBin[row] = NBINS - 1;
    nless[row] = (int)cum;
}

// Per-row finalize. NEW: boundary candidates are re-ranked by FLOAT64 distance
// sum((f-c)^2) — error ~1e-13 vs order-statistic gap ~0.04 => exact top-200 set,
// matching a float64 numpy reference regardless of fp32 summation order.
__global__ void __launch_bounds__(256)
k_final(const float* __restrict__ feat, const float* __restrict__ cent,
        const float* __restrict__ weightv, const int* __restrict__ labels,
        const float* __restrict__ gp, const int* __restrict__ candCnt,
        const Cand* __restrict__ cands, const int* __restrict__ nlessArr,
        float* __restrict__ out)
{
    __shared__ float  pcls[NCLS];      // 4000B
    __shared__ float  cw[CAND_MAX];    // fp32 d2 (for the weight)
    __shared__ int    cidx[CAND_MAX];
    __shared__ double cd2d[CAND_MAX];  // float64 exact d2 (for ranking)
    __shared__ double frow[DIM];
    __shared__ float  red[256];
    const int row = blockIdx.x;
    const int tid = threadIdx.x;

    for (int j = tid; j < NCLS; j += 256) pcls[j] = gp[(size_t)row * NCLS + j];
    for (int j = tid; j < DIM; j += 256) frow[j] = (double)feat[(size_t)row * DIM + j];
    int cnt = candCnt[row];
    if (cnt > CAND_MAX) cnt = CAND_MAX;
    const int need = KNN - nlessArr[row];
    for (int i = tid; i < cnt; i += 256) {
        cw[i]   = cands[(size_t)row * CAND_MAX + i].d2;
        cidx[i] = cands[(size_t)row * CAND_MAX + i].idx;
    }
    __syncthreads();

    // Exact (float64) distances for the boundary candidates.
    for (int i = tid; i < cnt; i += 256) {
        const float* c = cent + (size_t)cidx[i] * DIM;
        double s = 0.0;
        #pragma unroll 4
        for (int k = 0; k < DIM; ++k) {
            double dv = frow[k] - (double)c[k];
            s = fma(dv, dv, s);
        }
        cd2d[i] = s;
    }
    __syncthreads();

    // Rank by exact d2 (tie by idx); include the `need` smallest.
    for (int i = tid; i < cnt; i += 256) {
        double d = cd2d[i];
        int ix = cidx[i];
        int rank = 0;
        for (int j = 0; j < cnt; ++j) {
            double dj = cd2d[j];
            rank += (dj < d || (dj == d && cidx[j] < ix)) ? 1 : 0;
        }
        if (rank < need) {
            float w = expf(weightv[ix] - fmaxf(cw[i], 0.0f) * GCONST);
            atomicAdd(&pcls[labels[ix]], w);
        }
    }
    __syncthreads();

    float local = 0.0f;
    for (int j = tid; j < NCLS; j += 256) {
        float v = pcls[j];
        if (v == 0.0f) v = 1e-10f;
        pcls[j] = v;
        local += v;
    }
    red[tid] = local;
    __syncthreads();
    #pragma unroll
    for (int s = 128; s > 0; s >>= 1) {
        if (tid < s) red[tid] += red[tid + s];
        __syncthreads();
    }
    const float S = red[0];

    for (int j = tid; j < NCLS; j += 256) {
        float v = pcls[j] / S;
        out[(size_t)row * NCLS + j] = logf(v);                          // output 0: log(p)
        out[(size_t)NROWS * NCLS + (size_t)row * NCLS + j] = v;         // output 1: p
    }
}

extern "C" void kernel_launch(void* const* d_in, const int* in_sizes, int n_in,
                              void* d_out, int out_size, void* d_ws, size_t ws_size,
                              hipStream_t stream) {
    const float* feat       = (const float*)d_in[0];
    const float* cent       = (const float*)d_in[1];
    const float* weightv    = (const float*)d_in[2];
    const int*   labels_raw = (const int*)d_in[3];
    float*       out        = (float*)d_out;

    // Workspace bump allocator (512B aligned). Total ~19 MB.
    char* base = (char*)d_ws;
    size_t off = 0;
    auto alloc = [&](size_t bytes) -> void* {
        void* p = base + off;
        off = (off + bytes + 511) & ~(size_t)511;
        return p;
    };
    float*        cnorm    = (float*)alloc((size_t)NCENT * 4);
    float*        fnorm    = (float*)alloc((size_t)NROWS * 4);
    unsigned int* gHist    = (unsigned int*)alloc((size_t)NROWS * NBINS * 4);
    int*          tauBin   = (int*)alloc((size_t)NROWS * 4);
    int*          nless    = (int*)alloc((size_t)NROWS * 4);
    float*        gp       = (float*)alloc((size_t)NROWS * NCLS * 4);
    int*          candCnt  = (int*)alloc((size_t)NROWS * 4);
    Cand*         cands    = (Cand*)alloc((size_t)NROWS * CAND_MAX * sizeof(Cand));
    int*          labels32 = (int*)alloc((size_t)NCENT * 4);
    int*          lblFlag  = (int*)alloc(64);

    hipMemsetAsync(gHist, 0, (size_t)NROWS * NBINS * 4, stream);
    hipMemsetAsync(gp, 0, (size_t)NROWS * NCLS * 4, stream);
    hipMemsetAsync(candCnt, 0, (size_t)NROWS * 4, stream);

    k_detect<<<1, 64, 0, stream>>>(labels_raw, lblFlag);
    k_cvt_labels<<<(NCENT + 255) / 256, 256, 0, stream>>>((const void*)labels_raw, lblFlag, labels32);

    k_rownorm<<<NCENT / 4, 256, 0, stream>>>(cent, cnorm, NCENT);
    k_rownorm<<<NROWS / 4, 256, 0, stream>>>(feat, fnorm, NROWS);

    gemm_pass<1><<<dim3(NSTRIPS, NROWS / 64), 256, 0, stream>>>(
        feat, cent, weightv, labels32, fnorm, cnorm, gHist, nullptr, nullptr, nullptr, nullptr);

    k_tau<<<(NROWS + 255) / 256, 256, 0, stream>>>(gHist, tauBin, nless);

    gemm_pass<2><<<dim3(NSTRIPS, NROWS / 64), 256, 0, stream>>>(
        feat, cent, weightv, labels32, fnorm, cnorm, nullptr, tauBin, gp, candCnt, cands);

    k_final<<<NROWS, 256, 0, stream>>>(feat, cent, weightv, labels32, gp, candCnt, cands, nless, out);
}